// Round 1
// baseline (1042.729 us; speedup 1.0000x reference)
//
#include <hip/hip_runtime.h>
#include <hip/hip_bf16.h>

// Int8Linear: out[B,T,OUT] = x[B,T,IN] @ (w_int8*scale)^T + bias
// M = B*T = 8192, N = OUT = 11008, K = IN = 4096
#define MDIM 8192
#define NDIM 11008
#define KDIM 4096

#define BM 128
#define BN 128
#define BK 32

typedef __attribute__((ext_vector_type(8))) short short8;
typedef __attribute__((ext_vector_type(4))) float f32x4;

// ---------------- conversion kernels (memory-bound) ----------------

__device__ __forceinline__ unsigned short f2bf_rne(float f) {
  unsigned int u = __float_as_uint(f);
  u += 0x7fffu + ((u >> 16) & 1u);   // round-to-nearest-even
  return (unsigned short)(u >> 16);
}

__global__ void cvt_x_kernel(const float4* __restrict__ x,
                             ushort4* __restrict__ y, int n4) {
  int stride = gridDim.x * blockDim.x;
  for (int i = blockIdx.x * blockDim.x + threadIdx.x; i < n4; i += stride) {
    float4 v = x[i];
    ushort4 o;
    o.x = f2bf_rne(v.x); o.y = f2bf_rne(v.y);
    o.z = f2bf_rne(v.z); o.w = f2bf_rne(v.w);
    y[i] = o;
  }
}

// int8 values in [-127,127] are EXACT in bf16 (7 mantissa bits cover <=256)
__global__ void cvt_w_kernel(const int4* __restrict__ w,
                             ushort4* __restrict__ y, int n4) {
  int stride = gridDim.x * blockDim.x;
  for (int i = blockIdx.x * blockDim.x + threadIdx.x; i < n4; i += stride) {
    int4 v = w[i];
    ushort4 o;
    o.x = f2bf_rne((float)v.x); o.y = f2bf_rne((float)v.y);
    o.z = f2bf_rne((float)v.z); o.w = f2bf_rne((float)v.w);
    y[i] = o;
  }
}

// ---------------- bf16 MFMA GEMM (m97 structure) ----------------
// C[m,n] = scale[n] * sum_k A[m,k]*Bt[n,k] + bias[n]
// A: [M,K] bf16 row-major, Bt: [N,K] bf16 row-major, C: [M,N] fp32.

__global__ __launch_bounds__(256) void gemm_bf16_kernel(
    const unsigned short* __restrict__ A,
    const unsigned short* __restrict__ Bt,
    const float* __restrict__ scale,
    const float* __restrict__ bias,
    float* __restrict__ C)
{
  __shared__ __attribute__((aligned(16))) unsigned short As[BM * BK]; // 8 KB
  __shared__ __attribute__((aligned(16))) unsigned short Bs[BN * BK]; // 8 KB

  const int nbc = NDIM / BN; // 86 column-blocks; grid = 64*86 = 5504 = 8*688
  int bid = blockIdx.x;
  // XCD-aware bijective swizzle (nwg % 8 == 0)
  int cpx = gridDim.x >> 3;
  int swz = (bid & 7) * cpx + (bid >> 3);
  int brow = (swz / nbc) * BM;
  int bcol = (swz % nbc) * BN;

  int tid  = threadIdx.x;
  int lane = tid & 63;
  int wave = tid >> 6;
  int wr = (wave >> 1) * 64;  // wave's row offset in the 128x128 tile
  int wc = (wave & 1) * 64;   // wave's col offset

  // staging: 2 passes x 256 threads x 16B = 8 KB per tile.
  // flat byte index -> (row, col-byte) in the [128][32] bf16 tile (row = 64B)
  int flat0 = tid * 16;
  int flat1 = 4096 + tid * 16;
  const char* gA0 = (const char*)A  + (size_t)(brow + (flat0 >> 6)) * (KDIM * 2) + (flat0 & 63);
  const char* gA1 = (const char*)A  + (size_t)(brow + (flat1 >> 6)) * (KDIM * 2) + (flat1 & 63);
  const char* gB0 = (const char*)Bt + (size_t)(bcol + (flat0 >> 6)) * (KDIM * 2) + (flat0 & 63);
  const char* gB1 = (const char*)Bt + (size_t)(bcol + (flat1 >> 6)) * (KDIM * 2) + (flat1 & 63);

  // LDS dest is wave-uniform base (HW adds lane*16)
  char* lA = (char*)As;
  char* lB = (char*)Bs;
  unsigned dst0 = wave * 1024;
  unsigned dst1 = 4096 + wave * 1024;

  f32x4 acc[4][4] = {};

  int ra = lane & 15;            // fragment row (A) / col (B)
  int kb = (lane >> 4) * 16;     // byte offset along K within a tile row

  for (int kt = 0; kt < KDIM / BK; ++kt) {
    int koff = kt * (BK * 2);    // 64 bytes per K-step
    __builtin_amdgcn_global_load_lds(
        (const __attribute__((address_space(1))) void*)(gA0 + koff),
        (__attribute__((address_space(3))) void*)(lA + dst0), 16, 0, 0);
    __builtin_amdgcn_global_load_lds(
        (const __attribute__((address_space(1))) void*)(gA1 + koff),
        (__attribute__((address_space(3))) void*)(lA + dst1), 16, 0, 0);
    __builtin_amdgcn_global_load_lds(
        (const __attribute__((address_space(1))) void*)(gB0 + koff),
        (__attribute__((address_space(3))) void*)(lB + dst0), 16, 0, 0);
    __builtin_amdgcn_global_load_lds(
        (const __attribute__((address_space(1))) void*)(gB1 + koff),
        (__attribute__((address_space(3))) void*)(lB + dst1), 16, 0, 0);
    __syncthreads();  // drains vmcnt -> staged tile visible

    short8 af[4], bf[4];
#pragma unroll
    for (int m = 0; m < 4; ++m)
      af[m] = *(const short8*)(lA + ((wr + m * 16 + ra) * 64 + kb));
#pragma unroll
    for (int n = 0; n < 4; ++n)
      bf[n] = *(const short8*)(lB + ((wc + n * 16 + ra) * 64 + kb));

#pragma unroll
    for (int m = 0; m < 4; ++m)
#pragma unroll
      for (int n = 0; n < 4; ++n)
        acc[m][n] = __builtin_amdgcn_mfma_f32_16x16x32_bf16(af[m], bf[n], acc[m][n], 0, 0, 0);
    __syncthreads();
  }

  // epilogue: C/D layout col = lane&15, row = (lane>>4)*4 + reg
  int col0 = bcol + wc + ra;
  int row0 = brow + wr + (lane >> 4) * 4;
#pragma unroll
  for (int n = 0; n < 4; ++n) {
    int ng = col0 + n * 16;
    float sc = scale[ng];
    float bi = bias[ng];
#pragma unroll
    for (int m = 0; m < 4; ++m) {
      int rg = row0 + m * 16;
#pragma unroll
      for (int j = 0; j < 4; ++j)
        C[(size_t)(rg + j) * NDIM + ng] = acc[m][n][j] * sc + bi;
    }
  }
}

// ---------------- fallback (only if d_ws is too small) ----------------

__global__ void naive_kernel(const float* __restrict__ x, const int* __restrict__ w,
                             const float* __restrict__ scale, const float* __restrict__ bias,
                             float* __restrict__ out)
{
  int n = blockIdx.x * blockDim.x + threadIdx.x;
  int m = blockIdx.y;
  if (n >= NDIM) return;
  const float* xr = x + (size_t)m * KDIM;
  const int* wrow = w + (size_t)n * KDIM;
  float s = 0.f;
  for (int k = 0; k < KDIM; ++k) s += xr[k] * (float)wrow[k];
  out[(size_t)m * NDIM + n] = s * scale[n] + bias[n];
}

// ---------------- launcher ----------------

extern "C" void kernel_launch(void* const* d_in, const int* in_sizes, int n_in,
                              void* d_out, int out_size, void* d_ws, size_t ws_size,
                              hipStream_t stream) {
  const float* x      = (const float*)d_in[0];
  const int*   w8     = (const int*)d_in[1];
  const float* wscale = (const float*)d_in[2];
  const float* bias   = (const float*)d_in[3];
  float* out = (float*)d_out;

  size_t abytes = (size_t)MDIM * KDIM * 2;  // 67.1 MB
  size_t bbytes = (size_t)NDIM * KDIM * 2;  // 90.2 MB

  if (ws_size >= abytes + bbytes) {
    unsigned short* Abf = (unsigned short*)d_ws;
    unsigned short* Bbf = (unsigned short*)((char*)d_ws + abytes);
    int n4x = (MDIM * KDIM) / 4;
    int n4w = (NDIM * KDIM) / 4;
    cvt_x_kernel<<<2048, 256, 0, stream>>>((const float4*)x, (ushort4*)Abf, n4x);
    cvt_w_kernel<<<2048, 256, 0, stream>>>((const int4*)w8, (ushort4*)Bbf, n4w);
    gemm_bf16_kernel<<<(MDIM / BM) * (NDIM / BN), 256, 0, stream>>>(Abf, Bbf, wscale, bias, out);
  } else {
    naive_kernel<<<dim3((NDIM + 255) / 256, MDIM), 256, 0, stream>>>(x, w8, wscale, bias, out);
  }
}

// Round 2
// 845.837 us; speedup vs baseline: 1.2328x; 1.2328x over previous
//
#include <hip/hip_runtime.h>
#include <hip/hip_bf16.h>

// Int8Linear: out[B,T,OUT] = x[B,T,IN] @ (w_int8*scale)^T + bias
// M = B*T = 8192, N = OUT = 11008, K = IN = 4096
#define MDIM 8192
#define NDIM 11008
#define KDIM 4096

#define BM 256
#define BN 256
#define BK 64
#define NT (KDIM / BK)   // 64 K-tiles

typedef __attribute__((ext_vector_type(8))) short short8;
typedef __attribute__((ext_vector_type(4))) float f32x4;

// ---------------- conversion kernels (memory-bound) ----------------

__device__ __forceinline__ unsigned short f2bf_rne(float f) {
  unsigned int u = __float_as_uint(f);
  u += 0x7fffu + ((u >> 16) & 1u);   // round-to-nearest-even
  return (unsigned short)(u >> 16);
}

__global__ void cvt_x_kernel(const float4* __restrict__ x,
                             ushort4* __restrict__ y, int n4) {
  int stride = gridDim.x * blockDim.x;
  for (int i = blockIdx.x * blockDim.x + threadIdx.x; i < n4; i += stride) {
    float4 v = x[i];
    ushort4 o;
    o.x = f2bf_rne(v.x); o.y = f2bf_rne(v.y);
    o.z = f2bf_rne(v.z); o.w = f2bf_rne(v.w);
    y[i] = o;
  }
}

// int8 values in [-127,127] are EXACT in bf16
__global__ void cvt_w_kernel(const int4* __restrict__ w,
                             ushort4* __restrict__ y, int n4) {
  int stride = gridDim.x * blockDim.x;
  for (int i = blockIdx.x * blockDim.x + threadIdx.x; i < n4; i += stride) {
    int4 v = w[i];
    ushort4 o;
    o.x = f2bf_rne((float)v.x); o.y = f2bf_rne((float)v.y);
    o.z = f2bf_rne((float)v.z); o.w = f2bf_rne((float)v.w);
    y[i] = o;
  }
}

// ---------------- 256x256 deep-pipelined bf16 MFMA GEMM ----------------
// C[m,n] = scale[n] * sum_k A[m,k]*Bt[n,k] + bias[n]
// A: [M,K] bf16 row-major, Bt: [N,K] bf16 row-major, C: [M,N] fp32.
// 512 threads = 8 waves (2 M x 4 N); per-wave output 128x64.
// LDS: per operand [2 buf][2 khalf][256 rows][32 bf16] = 64 KB; total 128 KB.
// Schedule: 4 phases/K-tile; one 16KB (operand,khalf) unit staged per phase;
// counted vmcnt(8) at ph1/ph3 (never 0 in steady state); swizzled reads.

#define SBARR() __builtin_amdgcn_sched_barrier(0)
#define BARR()  __builtin_amdgcn_s_barrier()
#define LGK0()  asm volatile("s_waitcnt lgkmcnt(0)" ::: "memory")
#define VM8()   asm volatile("s_waitcnt vmcnt(8)" ::: "memory")
#define VM4()   asm volatile("s_waitcnt vmcnt(4)" ::: "memory")
#define VM0()   asm volatile("s_waitcnt vmcnt(0)" ::: "memory")

#define GLL(SRC, DST) \
  __builtin_amdgcn_global_load_lds( \
      (const __attribute__((address_space(1))) void*)(SRC), \
      (__attribute__((address_space(3))) void*)(DST), 16, 0, 0)

// stage one (operand, khalf) unit of K-tile T: 2 loads/thread, linear LDS dest
#define STAGE(GSRC, LBASE, UOFF, T, KH) do { \
    const char* _s = (GSRC) + (T) * 128 + (KH) * 64; \
    GLL(_s, (LBASE) + (UOFF) + w * 1024); \
    GLL(_s + rstep, (LBASE) + (UOFF) + w * 1024 + 8192); \
  } while (0)

// swizzled fragment read (16B = 8 bf16 along K for one row)
#define RD(LBASE, UOFF, ROW) \
  (*(const short8*)((LBASE) + (UOFF) + (ROW) * 64 + kbs))

#define MFMA16(MOFF) do { \
    _Pragma("unroll") for (int mi = 0; mi < 4; ++mi) \
    _Pragma("unroll") for (int ni = 0; ni < 4; ++ni) \
      acc[(MOFF) + mi][ni] = __builtin_amdgcn_mfma_f32_16x16x32_bf16( \
          af[mi], bf[ni], acc[(MOFF) + mi][ni], 0, 0, 0); \
  } while (0)

// One K-tile = 4 phases. B_ = buffer (compile-time 0/1). S1: stage (T+1).kh1,
// S0: stage (T+2).kh0. WL: tail -> drain vmcnt(0).
#define KTILE(T, B_, S1, S0, WL) do { \
    const int uA0 = ((B_) * 2 + 0) * 16384, uA1 = ((B_) * 2 + 1) * 16384; \
    const int vA1 = (((B_) ^ 1) * 2 + 1) * 16384; \
    /* ph0: A[mq0] kk0 + B kk0 ; stage (T+1).A.kh1 */ \
    _Pragma("unroll") for (int mi = 0; mi < 4; ++mi) af[mi] = RD(ldsA, uA0, arow0 + mi * 16); \
    _Pragma("unroll") for (int ni = 0; ni < 4; ++ni) bf[ni] = RD(ldsB, uA0, brow0 + ni * 16); \
    if (S1) STAGE(gAs, ldsA, vA1, (T) + 1, 1); \
    SBARR(); BARR(); LGK0(); SBARR(); \
    __builtin_amdgcn_s_setprio(1); MFMA16(0); __builtin_amdgcn_s_setprio(0); \
    SBARR(); BARR(); SBARR(); \
    /* ph1: A[mq1] kk0 (reuse bf) ; stage (T+1).B.kh1 ; vmcnt */ \
    _Pragma("unroll") for (int mi = 0; mi < 4; ++mi) af[mi] = RD(ldsA, uA0, arow0 + 64 + mi * 16); \
    if (S1) STAGE(gBs, ldsB, vA1, (T) + 1, 1); \
    SBARR(); BARR(); LGK0(); SBARR(); \
    __builtin_amdgcn_s_setprio(1); MFMA16(4); __builtin_amdgcn_s_setprio(0); \
    SBARR(); if (WL) { VM0(); } else { VM8(); } SBARR(); BARR(); SBARR(); \
    /* ph2: A[mq0] kk1 + B kk1 ; stage (T+2).A.kh0 */ \
    _Pragma("unroll") for (int mi = 0; mi < 4; ++mi) af[mi] = RD(ldsA, uA1, arow0 + mi * 16); \
    _Pragma("unroll") for (int ni = 0; ni < 4; ++ni) bf[ni] = RD(ldsB, uA1, brow0 + ni * 16); \
    if (S0) STAGE(gAs, ldsA, uA0, (T) + 2, 0); \
    SBARR(); BARR(); LGK0(); SBARR(); \
    __builtin_amdgcn_s_setprio(1); MFMA16(0); __builtin_amdgcn_s_setprio(0); \
    SBARR(); BARR(); SBARR(); \
    /* ph3: A[mq1] kk1 ; stage (T+2).B.kh0 ; vmcnt */ \
    _Pragma("unroll") for (int mi = 0; mi < 4; ++mi) af[mi] = RD(ldsA, uA1, arow0 + 64 + mi * 16); \
    if (S0) STAGE(gBs, ldsB, uA0, (T) + 2, 0); \
    SBARR(); BARR(); LGK0(); SBARR(); \
    __builtin_amdgcn_s_setprio(1); MFMA16(4); __builtin_amdgcn_s_setprio(0); \
    SBARR(); if (WL) { VM0(); } else { VM8(); } SBARR(); BARR(); SBARR(); \
  } while (0)

__global__ __launch_bounds__(512, 2) void gemm_bf16_kernel(
    const unsigned short* __restrict__ A,
    const unsigned short* __restrict__ Bt,
    const float* __restrict__ scale,
    const float* __restrict__ bias,
    float* __restrict__ C)
{
  // [buf][khalf][256 rows][32 bf16] per operand
  __shared__ __attribute__((aligned(16))) unsigned short As[2][2][256][32];
  __shared__ __attribute__((aligned(16))) unsigned short Bs[2][2][256][32];

  const int nbc = NDIM / BN;  // 43 ; grid = 32*43 = 1376 = 8*172
  int bid = blockIdx.x;
  int cpx = gridDim.x >> 3;
  int swz = (bid & 7) * cpx + (bid >> 3);   // bijective XCD swizzle
  int brow = (swz / nbc) * BM;
  int bcol = (swz % nbc) * BN;

  int tid  = threadIdx.x;
  int lane = tid & 63;
  int w    = tid >> 6;
  int wr   = (w >> 2) & 1;   // M-wave (2)
  int wc   = w & 3;          // N-wave (4)

  int ra = lane & 15;                         // fragment row within 16
  int kb = (lane >> 4) * 16;                  // byte offset along K (64B row)
  int kbs = kb ^ (((ra >> 1) & 3) << 4);      // T2 swizzled read offset

  int arow0 = wr * 128 + ra;                  // wave's A base row + frag row
  int brow0 = wc * 64 + ra;                   // wave's B base row + frag row

  // staging source: thread covers granule g = w*64+lane (rows 0-127) and
  // g+512 (rows 128-255); inverse-swizzled source column (lane-constant)
  int srow = w * 16 + (lane >> 2);
  int csrc = (lane & 3) ^ ((lane >> 3) & 3);
  const char* gAs = (const char*)A  + (size_t)(brow + srow) * (KDIM * 2) + csrc * 16;
  const char* gBs = (const char*)Bt + (size_t)(bcol + srow) * (KDIM * 2) + csrc * 16;
  const size_t rstep = (size_t)128 * KDIM * 2;

  char* ldsA = (char*)&As[0][0][0][0];
  char* ldsB = (char*)&Bs[0][0][0][0];

  f32x4 acc[8][4] = {};
  short8 af[4], bf[4];

  // prologue: tile0 fully + tile1.kh0 issued; wait leaves tile1.kh0 in flight
  STAGE(gAs, ldsA, 0,     0, 0);   // (0).A.kh0 -> As[0][0]
  STAGE(gBs, ldsB, 0,     0, 0);
  STAGE(gAs, ldsA, 16384, 0, 1);   // (0).A.kh1 -> As[0][1]
  STAGE(gBs, ldsB, 16384, 0, 1);
  STAGE(gAs, ldsA, 32768, 1, 0);   // (1).A.kh0 -> As[1][0]
  STAGE(gBs, ldsB, 32768, 1, 0);
  VM4(); SBARR(); BARR(); SBARR();

  // steady state: 31 iterations x 2 K-tiles, full staging, vmcnt(8)
  for (int it = 0; it < NT / 2 - 1; ++it) {
    int t = it * 2;
    KTILE(t,     0, 1, 1, 0);
    KTILE(t + 1, 1, 1, 1, 0);
  }
  // tail: drain
  KTILE(NT - 2, 0, 1, 0, 1);
  KTILE(NT - 1, 1, 0, 0, 1);

  // epilogue: C/D layout col = lane&15, row = (lane>>4)*4 + reg
  int col0 = bcol + wc * 64 + ra;
  int row0 = brow + wr * 128 + (lane >> 4) * 4;
#pragma unroll
  for (int n = 0; n < 4; ++n) {
    int ng = col0 + n * 16;
    float sc = scale[ng];
    float bi = bias[ng];
#pragma unroll
    for (int m = 0; m < 8; ++m) {
      int rg = row0 + m * 16;
#pragma unroll
      for (int j = 0; j < 4; ++j)
        C[(size_t)(rg + j) * NDIM + ng] = acc[m][n][j] * sc + bi;
    }
  }
}

// ---------------- fallback (only if d_ws is too small) ----------------

__global__ void naive_kernel(const float* __restrict__ x, const int* __restrict__ w,
                             const float* __restrict__ scale, const float* __restrict__ bias,
                             float* __restrict__ out)
{
  int n = blockIdx.x * blockDim.x + threadIdx.x;
  int m = blockIdx.y;
  if (n >= NDIM) return;
  const float* xr = x + (size_t)m * KDIM;
  const int* wrow = w + (size_t)n * KDIM;
  float s = 0.f;
  for (int k = 0; k < KDIM; ++k) s += xr[k] * (float)wrow[k];
  out[(size_t)m * NDIM + n] = s * scale[n] + bias[n];
}

// ---------------- launcher ----------------

extern "C" void kernel_launch(void* const* d_in, const int* in_sizes, int n_in,
                              void* d_out, int out_size, void* d_ws, size_t ws_size,
                              hipStream_t stream) {
  const float* x      = (const float*)d_in[0];
  const int*   w8     = (const int*)d_in[1];
  const float* wscale = (const float*)d_in[2];
  const float* bias   = (const float*)d_in[3];
  float* out = (float*)d_out;

  size_t abytes = (size_t)MDIM * KDIM * 2;  // 67.1 MB
  size_t bbytes = (size_t)NDIM * KDIM * 2;  // 90.2 MB

  if (ws_size >= abytes + bbytes) {
    unsigned short* Abf = (unsigned short*)d_ws;
    unsigned short* Bbf = (unsigned short*)((char*)d_ws + abytes);
    int n4x = (MDIM * KDIM) / 4;
    int n4w = (NDIM * KDIM) / 4;
    cvt_x_kernel<<<2048, 256, 0, stream>>>((const float4*)x, (ushort4*)Abf, n4x);
    cvt_w_kernel<<<2048, 256, 0, stream>>>((const int4*)w8, (ushort4*)Bbf, n4w);
    gemm_bf16_kernel<<<(MDIM / BM) * (NDIM / BN), 512, 0, stream>>>(Abf, Bbf, wscale, bias, out);
  } else {
    naive_kernel<<<dim3((NDIM + 255) / 256, MDIM), 256, 0, stream>>>(x, w8, wscale, bias, out);
  }
}

// Round 3
// 834.862 us; speedup vs baseline: 1.2490x; 1.0131x over previous
//
#include <hip/hip_runtime.h>
#include <hip/hip_bf16.h>

// Int8Linear: out[B,T,OUT] = x[B,T,IN] @ (w_int8*scale)^T + bias
// M = B*T = 8192, N = OUT = 11008, K = IN = 4096
#define MDIM 8192
#define NDIM 11008
#define KDIM 4096

#define BM 256
#define BN 256
#define BK 64
#define NT (KDIM / BK)   // 64 K-tiles

typedef __attribute__((ext_vector_type(8))) short short8;
typedef __attribute__((ext_vector_type(4))) float f32x4;

// ---------------- conversion kernels (memory-bound) ----------------

__device__ __forceinline__ unsigned short f2bf_rne(float f) {
  unsigned int u = __float_as_uint(f);
  u += 0x7fffu + ((u >> 16) & 1u);   // round-to-nearest-even
  return (unsigned short)(u >> 16);
}

__global__ void cvt_x_kernel(const float4* __restrict__ x,
                             ushort4* __restrict__ y, int n4) {
  int stride = gridDim.x * blockDim.x;
  for (int i = blockIdx.x * blockDim.x + threadIdx.x; i < n4; i += stride) {
    float4 v = x[i];
    ushort4 o;
    o.x = f2bf_rne(v.x); o.y = f2bf_rne(v.y);
    o.z = f2bf_rne(v.z); o.w = f2bf_rne(v.w);
    y[i] = o;
  }
}

// int8 values in [-127,127] are EXACT in bf16
__global__ void cvt_w_kernel(const int4* __restrict__ w,
                             ushort4* __restrict__ y, int n4) {
  int stride = gridDim.x * blockDim.x;
  for (int i = blockIdx.x * blockDim.x + threadIdx.x; i < n4; i += stride) {
    int4 v = w[i];
    ushort4 o;
    o.x = f2bf_rne((float)v.x); o.y = f2bf_rne((float)v.y);
    o.z = f2bf_rne((float)v.z); o.w = f2bf_rne((float)v.w);
    y[i] = o;
  }
}

// ---------------- 256x256 2-phase/K-tile bf16 MFMA GEMM ----------------
// C[m,n] = scale[n] * sum_k A[m,k]*Bt[n,k] + bias[n]
// 512 threads = 8 waves (2 M x 4 N); per-wave output 128x64.
// LDS: per operand [2 buf][2 khalf][256][32] bf16 = 64 KB; total 128 KB.
// Phase = {12 ds_read_b128 + 4 global_load_lds, MFMA x32, vmcnt(8), barrier}.
// Counted lgkm waits are compiler-inserted (plain C++ LDS loads).
// Steady invariant entering PH0(T): outstanding vm = [T.kh1(4), (T+1).kh0(4)].

#define SBARR() __builtin_amdgcn_sched_barrier(0)
#define BARR()  __builtin_amdgcn_s_barrier()
#define VMW_(n) asm volatile("s_waitcnt vmcnt(" #n ")" ::: "memory")
#define VMW(n)  VMW_(n)

#define GLL(SRC, DST) \
  __builtin_amdgcn_global_load_lds( \
      (const __attribute__((address_space(1))) void*)(SRC), \
      (__attribute__((address_space(3))) void*)(DST), 16, 0, 0)

// stage one (operand, khalf) unit of K-tile T: 2 loads/thread, linear LDS dest
#define STAGE(GSRC, LBASE, UOFF, T, KH) do { \
    const char* _s = (GSRC) + (T) * 128 + (KH) * 64; \
    GLL(_s, (LBASE) + (UOFF) + w * 1024); \
    GLL(_s + rstep, (LBASE) + (UOFF) + w * 1024 + 8192); \
  } while (0)

// swizzled fragment read (16B = 8 bf16 along K for one row)
#define RD(LBASE, UOFF, ROW) \
  (*(const short8*)((LBASE) + (UOFF) + (ROW) * 64 + kbs))

#define MFMA16(AF, MOFF) do { \
    _Pragma("unroll") for (int mi = 0; mi < 4; ++mi) \
    _Pragma("unroll") for (int ni = 0; ni < 4; ++ni) \
      acc[(MOFF) + mi][ni] = __builtin_amdgcn_mfma_f32_16x16x32_bf16( \
          AF[mi], bf[ni], acc[(MOFF) + mi][ni], 0, 0, 0); \
  } while (0)

// One phase. U = LDS unit byte offset for reads. SD = do stage, SU = stage LDS
// unit offset, ST/SK = staged tile/khalf. VN = vmcnt count. TAILP = skip wait+barrier.
#define PHASE(U, SD, SU, ST, SK, VN, TAILP) do { \
    _Pragma("unroll") for (int ni = 0; ni < 4; ++ni) bf[ni]  = RD(ldsB, U, brow0 + ni * 16); \
    _Pragma("unroll") for (int mi = 0; mi < 4; ++mi) af[mi]  = RD(ldsA, U, arow0 + mi * 16); \
    _Pragma("unroll") for (int mi = 0; mi < 4; ++mi) af2[mi] = RD(ldsA, U, arow0 + 64 + mi * 16); \
    if (SD) { STAGE(gAs, ldsA, SU, ST, SK); STAGE(gBs, ldsB, SU, ST, SK); } \
    SBARR(); \
    __builtin_amdgcn_s_setprio(1); \
    MFMA16(af, 0); \
    MFMA16(af2, 4); \
    __builtin_amdgcn_s_setprio(0); \
    SBARR(); \
    if (!(TAILP)) { VMW(VN); BARR(); SBARR(); } \
  } while (0)

// K-tile = 2 phases. PH0 reads kh0, stages (T+1).kh1 into buf^1.
// PH1 reads kh1, stages (T+2).kh0 into buf.
#define KTILE(T, B_, S1, S0, N0, N1, LAST) do { \
    PHASE((B_) * 32768,         S1, ((B_) ^ 1) * 32768 + 16384, (T) + 1, 1, N0, 0); \
    PHASE((B_) * 32768 + 16384, S0, (B_) * 32768,               (T) + 2, 0, N1, LAST); \
  } while (0)

__global__ __launch_bounds__(512, 2) void gemm_bf16_kernel(
    const unsigned short* __restrict__ A,
    const unsigned short* __restrict__ Bt,
    const float* __restrict__ scale,
    const float* __restrict__ bias,
    float* __restrict__ C)
{
  __shared__ __attribute__((aligned(16))) unsigned short As[2][2][256][32];
  __shared__ __attribute__((aligned(16))) unsigned short Bs[2][2][256][32];

  const int nbc = NDIM / BN;  // 43 ; grid = 32*43 = 1376 = 8*172
  int bid = blockIdx.x;
  int cpx = gridDim.x >> 3;
  int swz = (bid & 7) * cpx + (bid >> 3);   // bijective XCD swizzle
  int brow = (swz / nbc) * BM;
  int bcol = (swz % nbc) * BN;

  int tid  = threadIdx.x;
  int lane = tid & 63;
  int w    = tid >> 6;
  int wr   = (w >> 2) & 1;   // M-wave (2)
  int wc   = w & 3;          // N-wave (4)

  int ra = lane & 15;                         // fragment row within 16
  int kb = (lane >> 4) * 16;                  // byte offset along K (64B row)
  int kbs = kb ^ (((ra >> 1) & 3) << 4);      // T2 swizzled read offset

  int arow0 = wr * 128 + ra;                  // wave's A base row + frag row
  int brow0 = wc * 64 + ra;                   // wave's B base row + frag row

  // staging: thread covers granule g = w*64+lane (rows 0-127) and g+512;
  // inverse-swizzled source column (lane-constant)
  int srow = w * 16 + (lane >> 2);
  int csrc = (lane & 3) ^ ((lane >> 3) & 3);
  const char* gAs = (const char*)A  + (size_t)(brow + srow) * (KDIM * 2) + csrc * 16;
  const char* gBs = (const char*)Bt + (size_t)(bcol + srow) * (KDIM * 2) + csrc * 16;
  const size_t rstep = (size_t)128 * KDIM * 2;

  char* ldsA = (char*)&As[0][0][0][0];
  char* ldsB = (char*)&Bs[0][0][0][0];

  f32x4 acc[8][4] = {};
  short8 af[4], af2[4], bf[4];

  // prologue: t0.kh0, t0.kh1, t1.kh0 staged (12 loads); drain t0.kh0
  STAGE(gAs, ldsA, 0,     0, 0);  STAGE(gBs, ldsB, 0,     0, 0);
  STAGE(gAs, ldsA, 16384, 0, 1);  STAGE(gBs, ldsB, 16384, 0, 1);
  STAGE(gAs, ldsA, 32768, 1, 0);  STAGE(gBs, ldsB, 32768, 1, 0);
  VMW(8); BARR(); SBARR();

  // steady: T = 0..61
  for (int it = 0; it < NT / 2 - 1; ++it) {
    int t = it * 2;
    KTILE(t,     0, 1, 1, 8, 8, 0);
    KTILE(t + 1, 1, 1, 1, 8, 8, 0);
  }
  // tail: T = 62 (stage 63.kh1 only), T = 63 (no stage)
  KTILE(62, 0, 1, 0, 8, 4, 0);
  KTILE(63, 1, 0, 0, 0, 0, 1);

  // epilogue: C/D layout col = lane&15, row = (lane>>4)*4 + reg
  int col0 = bcol + wc * 64 + ra;
  int row0 = brow + wr * 128 + (lane >> 4) * 4;
#pragma unroll
  for (int n = 0; n < 4; ++n) {
    int ng = col0 + n * 16;
    float sc = scale[ng];
    float bi = bias[ng];
#pragma unroll
    for (int m = 0; m < 8; ++m) {
      int rg = row0 + m * 16;
#pragma unroll
      for (int j = 0; j < 4; ++j)
        C[(size_t)(rg + j) * NDIM + ng] = acc[m][n][j] * sc + bi;
    }
  }
}

// ---------------- fallback (only if d_ws is too small) ----------------

__global__ void naive_kernel(const float* __restrict__ x, const int* __restrict__ w,
                             const float* __restrict__ scale, const float* __restrict__ bias,
                             float* __restrict__ out)
{
  int n = blockIdx.x * blockDim.x + threadIdx.x;
  int m = blockIdx.y;
  if (n >= NDIM) return;
  const float* xr = x + (size_t)m * KDIM;
  const int* wrow = w + (size_t)n * KDIM;
  float s = 0.f;
  for (int k = 0; k < KDIM; ++k) s += xr[k] * (float)wrow[k];
  out[(size_t)m * NDIM + n] = s * scale[n] + bias[n];
}

// ---------------- launcher ----------------

extern "C" void kernel_launch(void* const* d_in, const int* in_sizes, int n_in,
                              void* d_out, int out_size, void* d_ws, size_t ws_size,
                              hipStream_t stream) {
  const float* x      = (const float*)d_in[0];
  const int*   w8     = (const int*)d_in[1];
  const float* wscale = (const float*)d_in[2];
  const float* bias   = (const float*)d_in[3];
  float* out = (float*)d_out;

  size_t abytes = (size_t)MDIM * KDIM * 2;  // 67.1 MB
  size_t bbytes = (size_t)NDIM * KDIM * 2;  // 90.2 MB

  if (ws_size >= abytes + bbytes) {
    unsigned short* Abf = (unsigned short*)d_ws;
    unsigned short* Bbf = (unsigned short*)((char*)d_ws + abytes);
    int n4x = (MDIM * KDIM) / 4;
    int n4w = (NDIM * KDIM) / 4;
    cvt_x_kernel<<<2048, 256, 0, stream>>>((const float4*)x, (ushort4*)Abf, n4x);
    cvt_w_kernel<<<2048, 256, 0, stream>>>((const int4*)w8, (ushort4*)Bbf, n4w);
    gemm_bf16_kernel<<<(MDIM / BM) * (NDIM / BN), 512, 0, stream>>>(Abf, Bbf, wscale, bias, out);
  } else {
    naive_kernel<<<dim3((NDIM + 255) / 256, MDIM), 256, 0, stream>>>(x, w8, wscale, bias, out);
  }
}